// Round 2
// baseline (3273.269 us; speedup 1.0000x reference)
//
#include <hip/hip_runtime.h>

#define B_ 8
#define H_ 96
#define W_ 96
#define C_ 384
#define SH_ 24
#define SW_ 24
#define M_ 576
#define N_ 9216
#define TEMP_ 0.01f

// ------------------------------------------------------------------
// K1: init centroids (4x4 block mean) + |s|^2 ; also init lab64 keys
// grid: B_*M_ blocks, 384 threads (thread = channel)
// ------------------------------------------------------------------
__global__ __launch_bounds__(384) void k_init(const float* __restrict__ pix,
                                              float* __restrict__ sp,
                                              float* __restrict__ sq,
                                              unsigned long long* __restrict__ lab64) {
  int gid = blockIdx.x * 384 + threadIdx.x;
  if (gid < N_ * B_) lab64[gid] = ~0ull;
  int bm = blockIdx.x;
  int b = bm / M_, m = bm % M_;
  int mh = m / SW_, mw = m % SW_;
  int c = threadIdx.x;
  const float* base = pix + (((size_t)(b * H_ + mh * 4)) * W_ + mw * 4) * C_ + c;
  float s = 0.f;
#pragma unroll
  for (int i = 0; i < 4; i++)
#pragma unroll
    for (int j = 0; j < 4; j++)
      s += base[(size_t)(i * W_ + j) * C_];
  s *= 0.0625f;
  sp[((size_t)(b * M_) + m) * C_ + c] = s;
  float q = s * s;
#pragma unroll
  for (int off = 32; off > 0; off >>= 1) q += __shfl_down(q, off);
  __shared__ float red[6];
  if ((c & 63) == 0) red[c >> 6] = q;
  __syncthreads();
  if (c == 0) sq[b * M_ + m] = red[0] + red[1] + red[2] + red[3] + red[4] + red[5];
}

#define DOT8(ACC, A, BV, SA, SB)                                              \
  ACC = fmaf((A).x, (SA).x, fmaf((A).y, (SA).y, fmaf((A).z, (SA).z,           \
        fmaf((A).w, (SA).w, fmaf((BV).x, (SB).x, fmaf((BV).y, (SB).y,         \
        fmaf((BV).z, (SB).z, fmaf((BV).w, (SB).w, ACC))))))))

// ------------------------------------------------------------------
// K2: raw window dots, channel-quartered.
// wg = (b, label-row lh, channel-quarter). 192 threads, 2 px/thread
// (same label block -> shared centroid reads). Window union for a full
// row = 5 dh-rows x 24 cols = 120 centroids; staged 48 channels at a
// time (LDS 120x52 f32 = 25KB). atomicAdd raw dot into dotb[B*N][25].
// ------------------------------------------------------------------
__global__ __launch_bounds__(192) void k_dot(const float* __restrict__ pix,
                                             const float* __restrict__ sp,
                                             float* __restrict__ dotb) {
  int wg = blockIdx.x;
  int b = wg / 96, r = wg % 96;
  int lh = r >> 2, quarter = r & 3;
  int qb = quarter * 96;
  __shared__ float sL[120 * 52];
  int t = threadIdx.x;
  int lw = t >> 3, pp = t & 7;
  int h1 = lh * 4 + (pp >> 2), w1 = lw * 4 + (pp & 3);
  int h2 = h1 + 2;
  const float* p1 = pix + (((size_t)(b * H_ + h1)) * W_ + w1) * C_ + qb;
  const float* p2 = pix + (((size_t)(b * H_ + h2)) * W_ + w1) * C_ + qb;
  int mwc[5];
#pragma unroll
  for (int dw = 0; dw < 5; dw++) {
    int v = lw - 2 + dw;
    mwc[dw] = v < 0 ? 0 : (v > 23 ? 23 : v);
  }
  float acc0[25], acc1[25];
#pragma unroll
  for (int k = 0; k < 25; k++) { acc0[k] = 0.f; acc1[k] = 0.f; }

  for (int stg = 0; stg < 2; stg++) {
    __syncthreads();
    int cb = stg * 48;
    for (int e = t; e < 120 * 12; e += 192) {
      int u = e / 12, c4 = e % 12;
      int mh = lh - 2 + u / 24, mw = u % 24;
      float4 v = make_float4(0.f, 0.f, 0.f, 0.f);
      if (mh >= 0 && mh < SH_)
        v = *(const float4*)(sp + ((size_t)(b * M_ + mh * SW_ + mw)) * C_ + qb + cb + c4 * 4);
      *(float4*)&sL[u * 52 + c4 * 4] = v;
    }
    __syncthreads();
    for (int c0 = 0; c0 < 48; c0 += 8) {
      float4 a0 = *(const float4*)(p1 + cb + c0);
      float4 b0 = *(const float4*)(p1 + cb + c0 + 4);
      float4 a1 = *(const float4*)(p2 + cb + c0);
      float4 b1 = *(const float4*)(p2 + cb + c0 + 4);
#pragma unroll
      for (int dh = 0; dh < 5; dh++) {
#pragma unroll
        for (int dw = 0; dw < 5; dw++) {
          const float* srow = &sL[(dh * 24 + mwc[dw]) * 52 + c0];
          float4 sa = *(const float4*)srow;
          float4 sb = *(const float4*)(srow + 4);
          int k = dh * 5 + dw;
          DOT8(acc0[k], a0, b0, sa, sb);
          DOT8(acc1[k], a1, b1, sa, sb);
        }
      }
    }
  }
  float* d1 = dotb + ((size_t)(b * N_) + h1 * W_ + w1) * 25;
  float* d2 = dotb + ((size_t)(b * N_) + h2 * W_ + w1) * 25;
#pragma unroll
  for (int k = 0; k < 25; k++) {
    atomicAdd(d1 + k, acc0[k]);
    atomicAdd(d2 + k, acc1[k]);
  }
}

// ------------------------------------------------------------------
// K3: in-place masked softmax over the 25 dot slots per pixel.
// logit = TEMP*(2*dot - |s|^2); invalid (border) slots -> -inf.
// ------------------------------------------------------------------
__global__ __launch_bounds__(256) void k_soft(float* __restrict__ buf,
                                              const float* __restrict__ sq) {
  int gid = blockIdx.x * 256 + threadIdx.x;
  int b = gid / N_, rem = gid % N_;
  int h = rem / W_, w = rem % W_;
  int lh = h >> 2, lw = w >> 2;
  float* row = buf + (size_t)gid * 25;
  float lg[25];
  float mx = -3.0e38f;
#pragma unroll
  for (int dh = 0; dh < 5; dh++) {
#pragma unroll
    for (int dw = 0; dw < 5; dw++) {
      int k = dh * 5 + dw;
      int mh = lh + dh - 2, mw = lw + dw - 2;
      bool valid = (mh >= 0) && (mh < SH_) && (mw >= 0) && (mw < SW_);
      float l = -3.0e38f;
      if (valid) l = TEMP_ * (2.f * row[k] - sq[b * M_ + mh * SW_ + mw]);
      lg[k] = l;
      mx = fmaxf(mx, l);
    }
  }
  float z = 0.f;
#pragma unroll
  for (int k = 0; k < 25; k++) {
    float e = __expf(lg[k] - mx);
    lg[k] = e;
    z += e;
  }
  float inv = 1.f / z;
#pragma unroll
  for (int k = 0; k < 25; k++) row[k] = lg[k] * inv;
}

// ------------------------------------------------------------------
// K4: scatter aggregation (unchanged structure). thread = channel,
// block-uniform aff rows -> scalar loads, register acc[5][16].
// ------------------------------------------------------------------
__global__ __launch_bounds__(384) void k_scatter(const float* __restrict__ pix,
                                                 const float* __restrict__ aff,
                                                 float* __restrict__ accum) {
  int wg = blockIdx.x;
  int b = wg / 48, r = wg % 48;
  int lh = r / 2, lw0 = (r % 2) * 12;
  int c = threadIdx.x;
  float acc[5][16];
#pragma unroll
  for (int a = 0; a < 5; a++)
#pragma unroll
    for (int w2 = 0; w2 < 16; w2++) acc[a][w2] = 0.f;
#pragma unroll
  for (int lwl = 0; lwl < 12; lwl++) {
    int lw = lw0 + lwl;
#pragma unroll 4
    for (int jj = 0; jj < 16; jj++) {
      int h = lh * 4 + (jj >> 2);
      int w = lw * 4 + (jj & 3);
      const float* ar = aff + ((size_t)(b * N_) + h * W_ + w) * 25;
      float val = pix[(((size_t)(b * H_) + h) * W_ + w) * C_ + c];
#pragma unroll
      for (int dh = 0; dh < 5; dh++)
#pragma unroll
        for (int dw = 0; dw < 5; dw++)
          acc[dh][lwl + dw] = fmaf(ar[dh * 5 + dw], val, acc[dh][lwl + dw]);
    }
  }
#pragma unroll
  for (int dh = 0; dh < 5; dh++) {
    int mh = lh - 2 + dh;
    if (mh < 0 || mh >= SH_) continue;
#pragma unroll
    for (int wi = 0; wi < 16; wi++) {
      int mw = lw0 - 2 + wi;
      if (mw < 0 || mw >= SW_) continue;
      atomicAdd(&accum[((size_t)(b * M_) + mh * SW_ + mw) * C_ + c], acc[dh][wi]);
    }
  }
}

// ------------------------------------------------------------------
// K5: finalize: denom = window gather-sum of aff, sp = accum/denom,
// sq = |s|^2. Block = (b,m), 384 threads.
// ------------------------------------------------------------------
__global__ __launch_bounds__(384) void k_fin(const float* __restrict__ aff,
                                             const float* __restrict__ accum,
                                             float* __restrict__ sp,
                                             float* __restrict__ sq) {
  int bm = blockIdx.x;
  int b = bm / M_, m = bm % M_;
  int mh = m / SW_, mw = m % SW_;
  int t = threadIdx.x;
  int h0 = (mh - 2) * 4; if (h0 < 0) h0 = 0;
  int h1 = (mh + 3) * 4; if (h1 > H_) h1 = H_;
  int w0 = (mw - 2) * 4; if (w0 < 0) w0 = 0;
  int w1 = (mw + 3) * 4; if (w1 > W_) w1 = W_;
  int nw = w1 - w0;
  int np = (h1 - h0) * nw;
  float d = 0.f;
  for (int e = t; e < np; e += 384) {
    int hh = h0 + e / nw, ww = w0 + e % nw;
    int k = (mh - (hh >> 2) + 2) * 5 + (mw - (ww >> 2) + 2);
    d += aff[((size_t)(b * N_) + hh * W_ + ww) * 25 + k];
  }
  __shared__ float red[6];
#pragma unroll
  for (int off = 32; off > 0; off >>= 1) d += __shfl_down(d, off);
  if ((t & 63) == 0) red[t >> 6] = d;
  __syncthreads();
  float denom = fmaxf(red[0] + red[1] + red[2] + red[3] + red[4] + red[5], 1e-16f);
  size_t idx = ((size_t)(b * M_) + m) * C_ + t;
  float sv = accum[idx] / denom;
  sp[idx] = sv;
  float q = sv * sv;
#pragma unroll
  for (int off = 32; off > 0; off >>= 1) q += __shfl_down(q, off);
  __syncthreads();
  if ((t & 63) == 0) red[t >> 6] = q;
  __syncthreads();
  if (t == 0) sq[b * M_ + m] = red[0] + red[1] + red[2] + red[3] + red[4] + red[5];
}

// ------------------------------------------------------------------
// K6: final unmasked argmin, M split into 5 chunks of 128 across
// blocks. 256 threads = 16 pxg x 16 cg; per-thread 8px x 8cand tile
// (16 FMA per ds_read_b128). Consistent (row>>3) XOR swizzle on 36-f
// rows. Partial (dist,idx) folded into ordered-u64 key, atomicMin.
// ------------------------------------------------------------------
__global__ __launch_bounds__(256) void k_argmin(const float* __restrict__ pix,
                                                const float* __restrict__ sp,
                                                const float* __restrict__ sq,
                                                unsigned long long* __restrict__ lab64) {
  int wg = blockIdx.x;
  int b = wg / 360;
  int r = wg % 360;
  int px0 = (r / 5) * 128;
  int m0 = (r % 5) * 128;
  __shared__ float pT[128 * 36];
  __shared__ float sT[128 * 36];
  __shared__ float sqT[128];
  int t = threadIdx.x;
  int pxg = t >> 4, cg = t & 15;
  if (t < 128) {
    int mm = m0 + t;
    sqT[t] = (mm < M_) ? sq[b * M_ + mm] : 3.0e38f;
  }
  float acc[8][8];
#pragma unroll
  for (int x = 0; x < 8; x++)
#pragma unroll
    for (int y = 0; y < 8; y++) acc[x][y] = 0.f;

  int srow_ = t >> 1, so_ = (t & 1) * 16;
  int ssw_ = (srow_ >> 3) & 7;
  int mrow_ = m0 + srow_; if (mrow_ > M_ - 1) mrow_ = M_ - 1;
  const float* psrc0 = pix + ((size_t)(b * N_) + px0 + srow_) * C_ + so_;
  const float* ssrc0 = sp + ((size_t)(b * M_) + mrow_) * C_ + so_;

  for (int k0 = 0; k0 < C_; k0 += 32) {
    __syncthreads();
#pragma unroll
    for (int jj = 0; jj < 4; jj++) {
      float4 v = *(const float4*)(psrc0 + k0 + jj * 4);
      float4 u = *(const float4*)(ssrc0 + k0 + jj * 4);
      int ob = (so_ >> 2) + jj;
      *(float4*)&pT[srow_ * 36 + (((ob ^ ssw_) & 7) << 2)] = v;
      *(float4*)&sT[srow_ * 36 + (((ob ^ ssw_) & 7) << 2)] = u;
    }
    __syncthreads();
#pragma unroll
    for (int q = 0; q < 8; q++) {
      float4 bb[8];
      int sb = (q ^ (cg & 7)) << 2;
#pragma unroll
      for (int y = 0; y < 8; y++)
        bb[y] = *(const float4*)&sT[(cg * 8 + y) * 36 + sb];
      int pb = (q ^ (pxg & 7)) << 2;
#pragma unroll
      for (int x = 0; x < 8; x++) {
        float4 av = *(const float4*)&pT[(pxg * 8 + x) * 36 + pb];
#pragma unroll
        for (int y = 0; y < 8; y++)
          acc[x][y] = fmaf(av.x, bb[y].x, fmaf(av.y, bb[y].y,
                      fmaf(av.z, bb[y].z, fmaf(av.w, bb[y].w, acc[x][y]))));
      }
    }
  }
  float best[8];
  int bidx[8];
#pragma unroll
  for (int x = 0; x < 8; x++) { best[x] = 3.4e38f; bidx[x] = 0; }
#pragma unroll
  for (int y = 0; y < 8; y++) {
    int m = m0 + cg * 8 + y;
    float dq = sqT[cg * 8 + y];
#pragma unroll
    for (int x = 0; x < 8; x++) {
      float d = dq - 2.f * acc[x][y];
      if (d < best[x]) { best[x] = d; bidx[x] = m; }
    }
  }
#pragma unroll
  for (int off = 1; off < 16; off <<= 1) {
#pragma unroll
    for (int x = 0; x < 8; x++) {
      float ov = __shfl_xor(best[x], off, 16);
      int oi = __shfl_xor(bidx[x], off, 16);
      if (ov < best[x] || (ov == best[x] && oi < bidx[x])) { best[x] = ov; bidx[x] = oi; }
    }
  }
  if (cg == 0) {
#pragma unroll
    for (int x = 0; x < 8; x++) {
      unsigned u = __float_as_uint(best[x]);
      unsigned k32 = (u & 0x80000000u) ? ~u : (u | 0x80000000u);
      unsigned long long key = ((unsigned long long)k32 << 32) | (unsigned)bidx[x];
      atomicMin(lab64 + (size_t)b * N_ + px0 + pxg * 8 + x, key);
    }
  }
}

// ------------------------------------------------------------------
// K7: keys -> float labels
// ------------------------------------------------------------------
__global__ __launch_bounds__(256) void k_label(const unsigned long long* __restrict__ lab64,
                                               float* __restrict__ lab) {
  int i = blockIdx.x * 256 + threadIdx.x;
  lab[i] = (float)(unsigned)(lab64[i] & 0xFFFFFFFFull);
}

// ------------------------------------------------------------------
// K8: copy sp -> out features
// ------------------------------------------------------------------
__global__ __launch_bounds__(256) void k_copy(const float4* __restrict__ src,
                                              float4* __restrict__ dst) {
  int i = blockIdx.x * 256 + threadIdx.x;
  dst[i] = src[i];
}

// ------------------------------------------------------------------
extern "C" void kernel_launch(void* const* d_in, const int* in_sizes, int n_in,
                              void* d_out, int out_size, void* d_ws, size_t ws_size,
                              hipStream_t stream) {
  const float* pix = (const float*)d_in[0];
  float* out = (float*)d_out;
  char* ws = (char*)d_ws;
  float* sp    = (float*)(ws);               // 7,077,888 B
  float* accum = (float*)(ws + 7077888);     // 7,077,888 B
  float* buf   = (float*)(ws + 14155776);    // 7,372,800 B (dots -> aff, in place)
  float* sq    = (float*)(ws + 21528576);    //    18,432 B
  // lab64 parked in d_out feature region (overwritten by k_copy at the end)
  unsigned long long* lab64 = (unsigned long long*)d_out;

  k_init<<<B_ * M_, 384, 0, stream>>>(pix, sp, sq, lab64);
  for (int it = 0; it < 5; it++) {
    hipMemsetAsync(accum, 0, 7077888 + 7372800, stream);  // accum + buf contiguous
    k_dot<<<768, 192, 0, stream>>>(pix, sp, buf);
    k_soft<<<288, 256, 0, stream>>>(buf, sq);
    k_scatter<<<384, 384, 0, stream>>>(pix, buf, accum);
    k_fin<<<B_ * M_, 384, 0, stream>>>(buf, accum, sp, sq);
  }
  k_argmin<<<2880, 256, 0, stream>>>(pix, sp, sq, lab64);
  k_label<<<288, 256, 0, stream>>>(lab64, out + 1769472);
  k_copy<<<1728, 256, 0, stream>>>((const float4*)sp, (float4*)out);
}

// Round 3
// 1743.991 us; speedup vs baseline: 1.8769x; 1.8769x over previous
//
#include <hip/hip_runtime.h>

#define B_ 8
#define H_ 96
#define W_ 96
#define C_ 384
#define SH_ 24
#define SW_ 24
#define M_ 576
#define N_ 9216
#define TEMP_ 0.01f

// ------------------------------------------------------------------
// K1: init centroids (4x4 block mean) + |s|^2 ; also init lab64 keys
// grid: B_*M_ blocks, 384 threads (thread = channel)
// ------------------------------------------------------------------
__global__ __launch_bounds__(384) void k_init(const float* __restrict__ pix,
                                              float* __restrict__ sp,
                                              float* __restrict__ sq,
                                              unsigned long long* __restrict__ lab64) {
  int gid = blockIdx.x * 384 + threadIdx.x;
  if (gid < N_ * B_) lab64[gid] = ~0ull;
  int bm = blockIdx.x;
  int b = bm / M_, m = bm % M_;
  int mh = m / SW_, mw = m % SW_;
  int c = threadIdx.x;
  const float* base = pix + (((size_t)(b * H_ + mh * 4)) * W_ + mw * 4) * C_ + c;
  float s = 0.f;
#pragma unroll
  for (int i = 0; i < 4; i++)
#pragma unroll
    for (int j = 0; j < 4; j++)
      s += base[(size_t)(i * W_ + j) * C_];
  s *= 0.0625f;
  sp[((size_t)(b * M_) + m) * C_ + c] = s;
  float q = s * s;
#pragma unroll
  for (int off = 32; off > 0; off >>= 1) q += __shfl_down(q, off);
  __shared__ float red[6];
  if ((c & 63) == 0) red[c >> 6] = q;
  __syncthreads();
  if (c == 0) sq[b * M_ + m] = red[0] + red[1] + red[2] + red[3] + red[4] + red[5];
}

// ------------------------------------------------------------------
// K2: affinities (round-1 structure, conflict-free LDS).
// wg = (b, lh, 8-wide lw block-third), 128 threads, 1 px/thread.
// Window union 5x12 = 60 centroids; staged 48 channels at a time
// (8 chunks, LDS 60x52 f32 = 12.5 KB; stride 52 -> 13 f4-slots/row,
// odd => consecutive rows hit distinct bank groups, conflict-free).
// logit = TEMP*(2*dot - |s|^2); masked softmax over 25 slots.
// ------------------------------------------------------------------
__global__ __launch_bounds__(128) void k_aff(const float* __restrict__ pix,
                                             const float* __restrict__ sp,
                                             const float* __restrict__ sq,
                                             float* __restrict__ aff) {
  int wg = blockIdx.x;
  int b = wg / 72, r = wg % 72;
  int lh = r / 3, lw0 = (r % 3) * 8;
  __shared__ float sL[60 * 52];
  __shared__ float sqL[60];
  int t = threadIdx.x;
  for (int e = t; e < 60; e += 128) {
    int mh = lh - 2 + e / 12, mw = lw0 - 2 + e % 12;
    sqL[e] = (mh >= 0 && mh < SH_ && mw >= 0 && mw < SW_) ? sq[b * M_ + mh * SW_ + mw] : 0.f;
  }
  int i = t >> 4, j = t & 15;
  int lw = lw0 + i;
  int h = lh * 4 + (j >> 2), w = lw * 4 + (j & 3);
  const float* prow = pix + (((size_t)(b * H_ + h)) * W_ + w) * C_;
  float acc[25];
#pragma unroll
  for (int k = 0; k < 25; k++) acc[k] = 0.f;

  for (int chunk = 0; chunk < 8; chunk++) {
    int cb = chunk * 48;
    __syncthreads();
    for (int e = t; e < 60 * 12; e += 128) {
      int u = e / 12, c4 = e % 12;
      int mh = lh - 2 + u / 12, mw = lw0 - 2 + u % 12;
      float4 v = make_float4(0.f, 0.f, 0.f, 0.f);
      if (mh >= 0 && mh < SH_ && mw >= 0 && mw < SW_)
        v = *(const float4*)(sp + ((size_t)(b * M_ + mh * SW_ + mw)) * C_ + cb + c4 * 4);
      *(float4*)&sL[u * 52 + c4 * 4] = v;
    }
    __syncthreads();
#pragma unroll
    for (int c0 = 0; c0 < 48; c0 += 8) {
      float4 pa = *(const float4*)(prow + cb + c0);
      float4 pb = *(const float4*)(prow + cb + c0 + 4);
#pragma unroll
      for (int dh = 0; dh < 5; dh++) {
#pragma unroll
        for (int dw = 0; dw < 5; dw++) {
          const float* srow = &sL[(dh * 12 + i + dw) * 52 + c0];
          float4 sa = *(const float4*)srow;
          float4 sb = *(const float4*)(srow + 4);
          float tsum = fmaf(pa.x, sa.x, fmaf(pa.y, sa.y, fmaf(pa.z, sa.z, pa.w * sa.w)));
          tsum = fmaf(pb.x, sb.x, fmaf(pb.y, sb.y, fmaf(pb.z, sb.z, fmaf(pb.w, sb.w, tsum))));
          acc[dh * 5 + dw] += tsum;
        }
      }
    }
  }
  // masked softmax over the 25 slots
  float lg[25];
  float mx = -3e38f;
#pragma unroll
  for (int dh = 0; dh < 5; dh++) {
#pragma unroll
    for (int dw = 0; dw < 5; dw++) {
      int k = dh * 5 + dw;
      int mh = lh - 2 + dh, mw = lw - 2 + dw;
      int u = dh * 12 + i + dw;
      bool valid = (mh >= 0) && (mh < SH_) && (mw >= 0) && (mw < SW_);
      float l = valid ? (TEMP_ * (2.f * acc[k] - sqL[u])) : -3e38f;
      lg[k] = l;
      mx = fmaxf(mx, l);
    }
  }
  float z = 0.f;
#pragma unroll
  for (int k = 0; k < 25; k++) {
    float e = __expf(lg[k] - mx);
    lg[k] = e;
    z += e;
  }
  float inv = 1.f / z;
  float* arow = aff + ((size_t)(b * N_) + h * W_ + w) * 25;
#pragma unroll
  for (int k = 0; k < 25; k++) arow[k] = lg[k] * inv;
}

// ------------------------------------------------------------------
// K3: scatter aggregation. thread = channel, block-uniform aff rows
// -> scalar loads, register acc[5][16], atomicAdd into accumulator.
// ------------------------------------------------------------------
__global__ __launch_bounds__(384) void k_scatter(const float* __restrict__ pix,
                                                 const float* __restrict__ aff,
                                                 float* __restrict__ accum) {
  int wg = blockIdx.x;
  int b = wg / 48, r = wg % 48;
  int lh = r / 2, lw0 = (r % 2) * 12;
  int c = threadIdx.x;
  float acc[5][16];
#pragma unroll
  for (int a = 0; a < 5; a++)
#pragma unroll
    for (int w2 = 0; w2 < 16; w2++) acc[a][w2] = 0.f;
#pragma unroll
  for (int lwl = 0; lwl < 12; lwl++) {
    int lw = lw0 + lwl;
#pragma unroll 4
    for (int jj = 0; jj < 16; jj++) {
      int h = lh * 4 + (jj >> 2);
      int w = lw * 4 + (jj & 3);
      const float* ar = aff + ((size_t)(b * N_) + h * W_ + w) * 25;
      float val = pix[(((size_t)(b * H_) + h) * W_ + w) * C_ + c];
#pragma unroll
      for (int dh = 0; dh < 5; dh++)
#pragma unroll
        for (int dw = 0; dw < 5; dw++)
          acc[dh][lwl + dw] = fmaf(ar[dh * 5 + dw], val, acc[dh][lwl + dw]);
    }
  }
#pragma unroll
  for (int dh = 0; dh < 5; dh++) {
    int mh = lh - 2 + dh;
    if (mh < 0 || mh >= SH_) continue;
#pragma unroll
    for (int wi = 0; wi < 16; wi++) {
      int mw = lw0 - 2 + wi;
      if (mw < 0 || mw >= SW_) continue;
      atomicAdd(&accum[((size_t)(b * M_) + mh * SW_ + mw) * C_ + c], acc[dh][wi]);
    }
  }
}

// ------------------------------------------------------------------
// K4: finalize: denom = window gather-sum of aff, sp = accum/denom,
// sq = |s|^2. Block = (b,m), 384 threads.
// ------------------------------------------------------------------
__global__ __launch_bounds__(384) void k_fin(const float* __restrict__ aff,
                                             const float* __restrict__ accum,
                                             float* __restrict__ sp,
                                             float* __restrict__ sq) {
  int bm = blockIdx.x;
  int b = bm / M_, m = bm % M_;
  int mh = m / SW_, mw = m % SW_;
  int t = threadIdx.x;
  int h0 = (mh - 2) * 4; if (h0 < 0) h0 = 0;
  int h1 = (mh + 3) * 4; if (h1 > H_) h1 = H_;
  int w0 = (mw - 2) * 4; if (w0 < 0) w0 = 0;
  int w1 = (mw + 3) * 4; if (w1 > W_) w1 = W_;
  int nw = w1 - w0;
  int np = (h1 - h0) * nw;
  float d = 0.f;
  for (int e = t; e < np; e += 384) {
    int hh = h0 + e / nw, ww = w0 + e % nw;
    int k = (mh - (hh >> 2) + 2) * 5 + (mw - (ww >> 2) + 2);
    d += aff[((size_t)(b * N_) + hh * W_ + ww) * 25 + k];
  }
  __shared__ float red[6];
#pragma unroll
  for (int off = 32; off > 0; off >>= 1) d += __shfl_down(d, off);
  if ((t & 63) == 0) red[t >> 6] = d;
  __syncthreads();
  float denom = fmaxf(red[0] + red[1] + red[2] + red[3] + red[4] + red[5], 1e-16f);
  size_t idx = ((size_t)(b * M_) + m) * C_ + t;
  float sv = accum[idx] / denom;
  sp[idx] = sv;
  float q = sv * sv;
#pragma unroll
  for (int off = 32; off > 0; off >>= 1) q += __shfl_down(q, off);
  __syncthreads();
  if ((t & 63) == 0) red[t >> 6] = q;
  __syncthreads();
  if (t == 0) sq[b * M_ + m] = red[0] + red[1] + red[2] + red[3] + red[4] + red[5];
}

// ------------------------------------------------------------------
// K5: final unmasked argmin. Block = 128 px x 128 cand (one of 5
// m-chunks). 4 waves = 2x2 of (64px x 64cand); lane = 8pxg x 8cg;
// thread tile 8px x 8cand. All LDS reads touch only 8 distinct
// 16B-lines (8-lane broadcast), XOR-swizzled (row>>3) on 36-f rows.
// Register-prefetch double-buffer on the 32-ch k-chunks. Partial
// results folded via ordered-u64 atomicMin (first-index tie-break).
// ------------------------------------------------------------------
__global__ __launch_bounds__(256) void k_argmin(const float* __restrict__ pix,
                                                const float* __restrict__ sp,
                                                const float* __restrict__ sq,
                                                unsigned long long* __restrict__ lab64) {
  int wg = blockIdx.x;
  int b = wg / 360;
  int r = wg % 360;
  int px0 = (r / 5) * 128;
  int m0 = (r % 5) * 128;
  __shared__ float pT[128 * 36];
  __shared__ float sT[128 * 36];
  __shared__ float sqT[128];
  int t = threadIdx.x;
  int wave = t >> 6, lane = t & 63;
  int wpx = wave >> 1, wc = wave & 1;
  int pxg = lane >> 3, cg = lane & 7;
  if (t < 128) {
    int mm = m0 + t;
    sqT[t] = (mm < M_) ? sq[b * M_ + mm] : 3.0e38f;
  }
  // staging: thread t owns row t>>1, f4-slots {(t&1)*4 .. +3}
  int srow = t >> 1;
  int sslot0 = (t & 1) * 4;
  int ssw = (srow >> 3) & 7;
  int mrow = m0 + srow; if (mrow > M_ - 1) mrow = M_ - 1;
  const float* psrc = pix + ((size_t)(b * N_) + px0 + srow) * C_ + sslot0 * 4;
  const float* ssrc = sp + ((size_t)(b * M_) + mrow) * C_ + sslot0 * 4;
  float* pdst = &pT[srow * 36];
  float* sdst = &sT[srow * 36];

  float acc[8][8];
#pragma unroll
  for (int x = 0; x < 8; x++)
#pragma unroll
    for (int y = 0; y < 8; y++) acc[x][y] = 0.f;

  float4 pr[4], sr[4];
#pragma unroll
  for (int jj = 0; jj < 4; jj++) {
    pr[jj] = *(const float4*)(psrc + jj * 4);
    sr[jj] = *(const float4*)(ssrc + jj * 4);
  }

  for (int k0 = 0; k0 < C_; k0 += 32) {
    __syncthreads();
#pragma unroll
    for (int jj = 0; jj < 4; jj++) {
      int slot = (sslot0 + jj) ^ ssw;
      *(float4*)&pdst[slot << 2] = pr[jj];
      *(float4*)&sdst[slot << 2] = sr[jj];
    }
    __syncthreads();
    if (k0 + 32 < C_) {
#pragma unroll
      for (int jj = 0; jj < 4; jj++) {
        pr[jj] = *(const float4*)(psrc + k0 + 32 + jj * 4);
        sr[jj] = *(const float4*)(ssrc + k0 + 32 + jj * 4);
      }
    }
#pragma unroll
    for (int q = 0; q < 8; q++) {
      float4 bb[8];
      int sb = (q ^ cg) << 2;
#pragma unroll
      for (int y = 0; y < 8; y++)
        bb[y] = *(const float4*)&sT[(wc * 64 + cg * 8 + y) * 36 + sb];
      int pb = (q ^ pxg) << 2;
#pragma unroll
      for (int x = 0; x < 8; x++) {
        float4 av = *(const float4*)&pT[(wpx * 64 + pxg * 8 + x) * 36 + pb];
#pragma unroll
        for (int y = 0; y < 8; y++)
          acc[x][y] = fmaf(av.x, bb[y].x, fmaf(av.y, bb[y].y,
                      fmaf(av.z, bb[y].z, fmaf(av.w, bb[y].w, acc[x][y]))));
      }
    }
  }
  float best[8];
  int bidx[8];
#pragma unroll
  for (int x = 0; x < 8; x++) { best[x] = 3.4e38f; bidx[x] = 0; }
#pragma unroll
  for (int y = 0; y < 8; y++) {
    int lc = wc * 64 + cg * 8 + y;
    int mi = m0 + lc;
    float dq = sqT[lc];
#pragma unroll
    for (int x = 0; x < 8; x++) {
      float d = dq - 2.f * acc[x][y];
      if (d < best[x]) { best[x] = d; bidx[x] = mi; }
    }
  }
#pragma unroll
  for (int off = 1; off < 8; off <<= 1) {
#pragma unroll
    for (int x = 0; x < 8; x++) {
      float ov = __shfl_xor(best[x], off);
      int oi = __shfl_xor(bidx[x], off);
      if (ov < best[x] || (ov == best[x] && oi < bidx[x])) { best[x] = ov; bidx[x] = oi; }
    }
  }
  if (cg == 0) {
#pragma unroll
    for (int x = 0; x < 8; x++) {
      unsigned u = __float_as_uint(best[x]);
      unsigned k32 = (u & 0x80000000u) ? ~u : (u | 0x80000000u);
      unsigned long long key = ((unsigned long long)k32 << 32) | (unsigned)bidx[x];
      atomicMin(lab64 + (size_t)b * N_ + px0 + wpx * 64 + pxg * 8 + x, key);
    }
  }
}

// ------------------------------------------------------------------
// K6: keys -> float labels
// ------------------------------------------------------------------
__global__ __launch_bounds__(256) void k_label(const unsigned long long* __restrict__ lab64,
                                               float* __restrict__ lab) {
  int i = blockIdx.x * 256 + threadIdx.x;
  lab[i] = (float)(unsigned)(lab64[i] & 0xFFFFFFFFull);
}

// ------------------------------------------------------------------
// K7: copy sp -> out features
// ------------------------------------------------------------------
__global__ __launch_bounds__(256) void k_copy(const float4* __restrict__ src,
                                              float4* __restrict__ dst) {
  int i = blockIdx.x * 256 + threadIdx.x;
  dst[i] = src[i];
}

// ------------------------------------------------------------------
extern "C" void kernel_launch(void* const* d_in, const int* in_sizes, int n_in,
                              void* d_out, int out_size, void* d_ws, size_t ws_size,
                              hipStream_t stream) {
  const float* pix = (const float*)d_in[0];
  float* out = (float*)d_out;
  char* ws = (char*)d_ws;
  float* sp    = (float*)(ws);               // 7,077,888 B
  float* accum = (float*)(ws + 7077888);     // 7,077,888 B
  float* aff   = (float*)(ws + 14155776);    // 7,372,800 B
  float* sq    = (float*)(ws + 21528576);    //    18,432 B
  unsigned long long* lab64 = (unsigned long long*)d_out;  // scratch, overwritten by k_copy

  k_init<<<B_ * M_, 384, 0, stream>>>(pix, sp, sq, lab64);
  for (int it = 0; it < 5; it++) {
    hipMemsetAsync(accum, 0, 7077888, stream);
    k_aff<<<576, 128, 0, stream>>>(pix, sp, sq, aff);
    k_scatter<<<384, 384, 0, stream>>>(pix, aff, accum);
    k_fin<<<B_ * M_, 384, 0, stream>>>(aff, accum, sp, sq);
  }
  k_argmin<<<2880, 256, 0, stream>>>(pix, sp, sq, lab64);
  k_label<<<288, 256, 0, stream>>>(lab64, out + 1769472);
  k_copy<<<1728, 256, 0, stream>>>((const float4*)sp, (float4*)out);
}

// Round 4
// 1608.836 us; speedup vs baseline: 2.0346x; 1.0840x over previous
//
#include <hip/hip_runtime.h>

#define B_ 8
#define H_ 96
#define W_ 96
#define C_ 384
#define SH_ 24
#define SW_ 24
#define M_ 576
#define N_ 9216
#define TEMP_ 0.01f

// ------------------------------------------------------------------
// K1: init centroids (4x4 block mean) + |s|^2 ; also init lab64 keys
// grid: B_*M_ blocks, 384 threads (thread = channel)
// ------------------------------------------------------------------
__global__ __launch_bounds__(384) void k_init(const float* __restrict__ pix,
                                              float* __restrict__ sp,
                                              float* __restrict__ sq,
                                              unsigned long long* __restrict__ lab64) {
  int gid = blockIdx.x * 384 + threadIdx.x;
  if (gid < N_ * B_) lab64[gid] = ~0ull;
  int bm = blockIdx.x;
  int b = bm / M_, m = bm % M_;
  int mh = m / SW_, mw = m % SW_;
  int c = threadIdx.x;
  const float* base = pix + (((size_t)(b * H_ + mh * 4)) * W_ + mw * 4) * C_ + c;
  float s = 0.f;
#pragma unroll
  for (int i = 0; i < 4; i++)
#pragma unroll
    for (int j = 0; j < 4; j++)
      s += base[(size_t)(i * W_ + j) * C_];
  s *= 0.0625f;
  sp[((size_t)(b * M_) + m) * C_ + c] = s;
  float q = s * s;
#pragma unroll
  for (int off = 32; off > 0; off >>= 1) q += __shfl_down(q, off);
  __shared__ float red[6];
  if ((c & 63) == 0) red[c >> 6] = q;
  __syncthreads();
  if (c == 0) sq[b * M_ + m] = red[0] + red[1] + red[2] + red[3] + red[4] + red[5];
}

// ------------------------------------------------------------------
// K2: affinities (unchanged from round 3 — isolating the k_argmin fix).
// wg = (b, lh, 8-wide lw block-third), 128 threads, 1 px/thread.
// Window union 5x12 = 60 centroids; staged 48 channels at a time
// (8 chunks, LDS 60x52 f32 = 12.5 KB; odd f4-stride -> conflict-free).
// logit = TEMP*(2*dot - |s|^2); masked softmax over 25 slots.
// ------------------------------------------------------------------
__global__ __launch_bounds__(128) void k_aff(const float* __restrict__ pix,
                                             const float* __restrict__ sp,
                                             const float* __restrict__ sq,
                                             float* __restrict__ aff) {
  int wg = blockIdx.x;
  int b = wg / 72, r = wg % 72;
  int lh = r / 3, lw0 = (r % 3) * 8;
  __shared__ float sL[60 * 52];
  __shared__ float sqL[60];
  int t = threadIdx.x;
  for (int e = t; e < 60; e += 128) {
    int mh = lh - 2 + e / 12, mw = lw0 - 2 + e % 12;
    sqL[e] = (mh >= 0 && mh < SH_ && mw >= 0 && mw < SW_) ? sq[b * M_ + mh * SW_ + mw] : 0.f;
  }
  int i = t >> 4, j = t & 15;
  int lw = lw0 + i;
  int h = lh * 4 + (j >> 2), w = lw * 4 + (j & 3);
  const float* prow = pix + (((size_t)(b * H_ + h)) * W_ + w) * C_;
  float acc[25];
#pragma unroll
  for (int k = 0; k < 25; k++) acc[k] = 0.f;

  for (int chunk = 0; chunk < 8; chunk++) {
    int cb = chunk * 48;
    __syncthreads();
    for (int e = t; e < 60 * 12; e += 128) {
      int u = e / 12, c4 = e % 12;
      int mh = lh - 2 + u / 12, mw = lw0 - 2 + u % 12;
      float4 v = make_float4(0.f, 0.f, 0.f, 0.f);
      if (mh >= 0 && mh < SH_ && mw >= 0 && mw < SW_)
        v = *(const float4*)(sp + ((size_t)(b * M_ + mh * SW_ + mw)) * C_ + cb + c4 * 4);
      *(float4*)&sL[u * 52 + c4 * 4] = v;
    }
    __syncthreads();
#pragma unroll
    for (int c0 = 0; c0 < 48; c0 += 8) {
      float4 pa = *(const float4*)(prow + cb + c0);
      float4 pb = *(const float4*)(prow + cb + c0 + 4);
#pragma unroll
      for (int dh = 0; dh < 5; dh++) {
#pragma unroll
        for (int dw = 0; dw < 5; dw++) {
          const float* srow = &sL[(dh * 12 + i + dw) * 52 + c0];
          float4 sa = *(const float4*)srow;
          float4 sb = *(const float4*)(srow + 4);
          float tsum = fmaf(pa.x, sa.x, fmaf(pa.y, sa.y, fmaf(pa.z, sa.z, pa.w * sa.w)));
          tsum = fmaf(pb.x, sb.x, fmaf(pb.y, sb.y, fmaf(pb.z, sb.z, fmaf(pb.w, sb.w, tsum))));
          acc[dh * 5 + dw] += tsum;
        }
      }
    }
  }
  // masked softmax over the 25 slots
  float lg[25];
  float mx = -3e38f;
#pragma unroll
  for (int dh = 0; dh < 5; dh++) {
#pragma unroll
    for (int dw = 0; dw < 5; dw++) {
      int k = dh * 5 + dw;
      int mh = lh - 2 + dh, mw = lw - 2 + dw;
      int u = dh * 12 + i + dw;
      bool valid = (mh >= 0) && (mh < SH_) && (mw >= 0) && (mw < SW_);
      float l = valid ? (TEMP_ * (2.f * acc[k] - sqL[u])) : -3e38f;
      lg[k] = l;
      mx = fmaxf(mx, l);
    }
  }
  float z = 0.f;
#pragma unroll
  for (int k = 0; k < 25; k++) {
    float e = __expf(lg[k] - mx);
    lg[k] = e;
    z += e;
  }
  float inv = 1.f / z;
  float* arow = aff + ((size_t)(b * N_) + h * W_ + w) * 25;
#pragma unroll
  for (int k = 0; k < 25; k++) arow[k] = lg[k] * inv;
}

// ------------------------------------------------------------------
// K3: scatter aggregation (unchanged). thread = channel, block-uniform
// aff rows -> scalar loads, register acc[5][16], atomicAdd.
// ------------------------------------------------------------------
__global__ __launch_bounds__(384) void k_scatter(const float* __restrict__ pix,
                                                 const float* __restrict__ aff,
                                                 float* __restrict__ accum) {
  int wg = blockIdx.x;
  int b = wg / 48, r = wg % 48;
  int lh = r / 2, lw0 = (r % 2) * 12;
  int c = threadIdx.x;
  float acc[5][16];
#pragma unroll
  for (int a = 0; a < 5; a++)
#pragma unroll
    for (int w2 = 0; w2 < 16; w2++) acc[a][w2] = 0.f;
#pragma unroll
  for (int lwl = 0; lwl < 12; lwl++) {
    int lw = lw0 + lwl;
#pragma unroll 4
    for (int jj = 0; jj < 16; jj++) {
      int h = lh * 4 + (jj >> 2);
      int w = lw * 4 + (jj & 3);
      const float* ar = aff + ((size_t)(b * N_) + h * W_ + w) * 25;
      float val = pix[(((size_t)(b * H_) + h) * W_ + w) * C_ + c];
#pragma unroll
      for (int dh = 0; dh < 5; dh++)
#pragma unroll
        for (int dw = 0; dw < 5; dw++)
          acc[dh][lwl + dw] = fmaf(ar[dh * 5 + dw], val, acc[dh][lwl + dw]);
    }
  }
#pragma unroll
  for (int dh = 0; dh < 5; dh++) {
    int mh = lh - 2 + dh;
    if (mh < 0 || mh >= SH_) continue;
#pragma unroll
    for (int wi = 0; wi < 16; wi++) {
      int mw = lw0 - 2 + wi;
      if (mw < 0 || mw >= SW_) continue;
      atomicAdd(&accum[((size_t)(b * M_) + mh * SW_ + mw) * C_ + c], acc[dh][wi]);
    }
  }
}

// ------------------------------------------------------------------
// K4: finalize (unchanged): denom = window gather-sum of aff,
// sp = accum/denom, sq = |s|^2. Block = (b,m), 384 threads.
// ------------------------------------------------------------------
__global__ __launch_bounds__(384) void k_fin(const float* __restrict__ aff,
                                             const float* __restrict__ accum,
                                             float* __restrict__ sp,
                                             float* __restrict__ sq) {
  int bm = blockIdx.x;
  int b = bm / M_, m = bm % M_;
  int mh = m / SW_, mw = m % SW_;
  int t = threadIdx.x;
  int h0 = (mh - 2) * 4; if (h0 < 0) h0 = 0;
  int h1 = (mh + 3) * 4; if (h1 > H_) h1 = H_;
  int w0 = (mw - 2) * 4; if (w0 < 0) w0 = 0;
  int w1 = (mw + 3) * 4; if (w1 > W_) w1 = W_;
  int nw = w1 - w0;
  int np = (h1 - h0) * nw;
  float d = 0.f;
  for (int e = t; e < np; e += 384) {
    int hh = h0 + e / nw, ww = w0 + e % nw;
    int k = (mh - (hh >> 2) + 2) * 5 + (mw - (ww >> 2) + 2);
    d += aff[((size_t)(b * N_) + hh * W_ + ww) * 25 + k];
  }
  __shared__ float red[6];
#pragma unroll
  for (int off = 32; off > 0; off >>= 1) d += __shfl_down(d, off);
  if ((t & 63) == 0) red[t >> 6] = d;
  __syncthreads();
  float denom = fmaxf(red[0] + red[1] + red[2] + red[3] + red[4] + red[5], 1e-16f);
  size_t idx = ((size_t)(b * M_) + m) * C_ + t;
  float sv = accum[idx] / denom;
  sp[idx] = sv;
  float q = sv * sv;
#pragma unroll
  for (int off = 32; off > 0; off >>= 1) q += __shfl_down(q, off);
  __syncthreads();
  if ((t & 63) == 0) red[t >> 6] = q;
  __syncthreads();
  if (t == 0) sq[b * M_ + m] = red[0] + red[1] + red[2] + red[3] + red[4] + red[5];
}

// ------------------------------------------------------------------
// K5: final unmasked argmin — NO-SPILL restructure.
// Block = 128 px x 128 cand (one of 5 m-chunks). 4 waves = 2x2 of
// (64px x 64cand); lane = 8pxg x 8cg; thread tile 8px x 8cand.
// Register schedule: acc[8][8]=64 + av[8]=32 + bbv=4 (~114 live);
// __launch_bounds__(256,3) caps VGPR at 170 -> spill-impossible.
// No register prefetch (that caused round-3's 1 GB scratch traffic).
// Conflict-free: 8-lane-broadcast reads, (row>>3) XOR swizzle.
// Partials folded via ordered-u64 atomicMin (first-index tie-break).
// ------------------------------------------------------------------
__global__ __launch_bounds__(256, 3) void k_argmin(const float* __restrict__ pix,
                                                   const float* __restrict__ sp,
                                                   const float* __restrict__ sq,
                                                   unsigned long long* __restrict__ lab64) {
  int wg = blockIdx.x;
  int b = wg / 360;
  int r = wg % 360;
  int px0 = (r / 5) * 128;
  int m0 = (r % 5) * 128;
  __shared__ float pT[128 * 36];
  __shared__ float sT[128 * 36];
  __shared__ float sqT[128];
  int t = threadIdx.x;
  int wave = t >> 6, lane = t & 63;
  int wpx = wave >> 1, wc = wave & 1;
  int pxg = lane >> 3, cg = lane & 7;
  if (t < 128) {
    int mm = m0 + t;
    sqT[t] = (mm < M_) ? sq[b * M_ + mm] : 3.0e38f;
  }
  // staging: thread t owns row t>>1, f4-slots {(t&1)*4 .. +3}
  int srow = t >> 1;
  int sslot0 = (t & 1) * 4;
  int ssw = (srow >> 3) & 7;
  int mrow = m0 + srow; if (mrow > M_ - 1) mrow = M_ - 1;
  const float* psrc = pix + ((size_t)(b * N_) + px0 + srow) * C_ + sslot0 * 4;
  const float* ssrc = sp + ((size_t)(b * M_) + mrow) * C_ + sslot0 * 4;
  float* pdst = &pT[srow * 36];
  float* sdst = &sT[srow * 36];
  int pbase = (wpx * 64 + pxg * 8) * 36;
  int bbase = (wc * 64 + cg * 8) * 36;

  float acc[8][8];
#pragma unroll
  for (int x = 0; x < 8; x++)
#pragma unroll
    for (int y = 0; y < 8; y++) acc[x][y] = 0.f;

  for (int k0 = 0; k0 < C_; k0 += 32) {
    __syncthreads();
    {
      float4 t0 = *(const float4*)(psrc + k0);
      float4 t1 = *(const float4*)(psrc + k0 + 4);
      float4 t2 = *(const float4*)(psrc + k0 + 8);
      float4 t3 = *(const float4*)(psrc + k0 + 12);
      float4 u0 = *(const float4*)(ssrc + k0);
      float4 u1 = *(const float4*)(ssrc + k0 + 4);
      float4 u2 = *(const float4*)(ssrc + k0 + 8);
      float4 u3 = *(const float4*)(ssrc + k0 + 12);
      *(float4*)&pdst[((sslot0 + 0) ^ ssw) << 2] = t0;
      *(float4*)&pdst[((sslot0 + 1) ^ ssw) << 2] = t1;
      *(float4*)&pdst[((sslot0 + 2) ^ ssw) << 2] = t2;
      *(float4*)&pdst[((sslot0 + 3) ^ ssw) << 2] = t3;
      *(float4*)&sdst[((sslot0 + 0) ^ ssw) << 2] = u0;
      *(float4*)&sdst[((sslot0 + 1) ^ ssw) << 2] = u1;
      *(float4*)&sdst[((sslot0 + 2) ^ ssw) << 2] = u2;
      *(float4*)&sdst[((sslot0 + 3) ^ ssw) << 2] = u3;
    }
    __syncthreads();
#pragma unroll
    for (int q = 0; q < 8; q++) {
      float4 av[8];
      int pb = (q ^ pxg) << 2;
#pragma unroll
      for (int x = 0; x < 8; x++)
        av[x] = *(const float4*)&pT[pbase + x * 36 + pb];
      int sb = (q ^ cg) << 2;
#pragma unroll
      for (int y = 0; y < 8; y++) {
        float4 bbv = *(const float4*)&sT[bbase + y * 36 + sb];
#pragma unroll
        for (int x = 0; x < 8; x++)
          acc[x][y] = fmaf(av[x].x, bbv.x, fmaf(av[x].y, bbv.y,
                      fmaf(av[x].z, bbv.z, fmaf(av[x].w, bbv.w, acc[x][y]))));
      }
    }
  }
  float best[8];
  int bidx[8];
#pragma unroll
  for (int x = 0; x < 8; x++) { best[x] = 3.4e38f; bidx[x] = 0; }
#pragma unroll
  for (int y = 0; y < 8; y++) {
    int lc = wc * 64 + cg * 8 + y;
    int mi = m0 + lc;
    float dq = sqT[lc];
#pragma unroll
    for (int x = 0; x < 8; x++) {
      float d = dq - 2.f * acc[x][y];
      if (d < best[x]) { best[x] = d; bidx[x] = mi; }
    }
  }
#pragma unroll
  for (int off = 1; off < 8; off <<= 1) {
#pragma unroll
    for (int x = 0; x < 8; x++) {
      float ov = __shfl_xor(best[x], off);
      int oi = __shfl_xor(bidx[x], off);
      if (ov < best[x] || (ov == best[x] && oi < bidx[x])) { best[x] = ov; bidx[x] = oi; }
    }
  }
  if (cg == 0) {
#pragma unroll
    for (int x = 0; x < 8; x++) {
      unsigned u = __float_as_uint(best[x]);
      unsigned k32 = (u & 0x80000000u) ? ~u : (u | 0x80000000u);
      unsigned long long key = ((unsigned long long)k32 << 32) | (unsigned)bidx[x];
      atomicMin(lab64 + (size_t)b * N_ + px0 + wpx * 64 + pxg * 8 + x, key);
    }
  }
}

// ------------------------------------------------------------------
// K6: keys -> float labels
// ------------------------------------------------------------------
__global__ __launch_bounds__(256) void k_label(const unsigned long long* __restrict__ lab64,
                                               float* __restrict__ lab) {
  int i = blockIdx.x * 256 + threadIdx.x;
  lab[i] = (float)(unsigned)(lab64[i] & 0xFFFFFFFFull);
}

// ------------------------------------------------------------------
// K7: copy sp -> out features
// ------------------------------------------------------------------
__global__ __launch_bounds__(256) void k_copy(const float4* __restrict__ src,
                                              float4* __restrict__ dst) {
  int i = blockIdx.x * 256 + threadIdx.x;
  dst[i] = src[i];
}

// ------------------------------------------------------------------
extern "C" void kernel_launch(void* const* d_in, const int* in_sizes, int n_in,
                              void* d_out, int out_size, void* d_ws, size_t ws_size,
                              hipStream_t stream) {
  const float* pix = (const float*)d_in[0];
  float* out = (float*)d_out;
  char* ws = (char*)d_ws;
  float* sp    = (float*)(ws);               // 7,077,888 B
  float* accum = (float*)(ws + 7077888);     // 7,077,888 B
  float* aff   = (float*)(ws + 14155776);    // 7,372,800 B
  float* sq    = (float*)(ws + 21528576);    //    18,432 B
  unsigned long long* lab64 = (unsigned long long*)d_out;  // scratch, overwritten by k_copy

  k_init<<<B_ * M_, 384, 0, stream>>>(pix, sp, sq, lab64);
  for (int it = 0; it < 5; it++) {
    hipMemsetAsync(accum, 0, 7077888, stream);
    k_aff<<<576, 128, 0, stream>>>(pix, sp, sq, aff);
    k_scatter<<<384, 384, 0, stream>>>(pix, aff, accum);
    k_fin<<<B_ * M_, 384, 0, stream>>>(aff, accum, sp, sq);
  }
  k_argmin<<<2880, 256, 0, stream>>>(pix, sp, sq, lab64);
  k_label<<<288, 256, 0, stream>>>(lab64, out + 1769472);
  k_copy<<<1728, 256, 0, stream>>>((const float4*)sp, (float4*)out);
}